// Round 3
// baseline (497.699 us; speedup 1.0000x reference)
//
#include <hip/hip_runtime.h>

// GCN 3-layer: out = GCNconv3(relu(GCNconv2(relu(GCNconv1(x)))))
//
// R3 pipeline:
//   1. memset count[N*pad]      (pad = counters spread 1-per-64B-line; atomics
//                                to count were line-serialized: 16 ctr/line x
//                                32 hits = 512 atomics/line in R2)
//   2. fill_direct: pos = atomicAdd(count[d*pad]); bucket[d*C+pos] = {src, ew}
//   3. deg_dinv: per-node reduce of bucket ew -> dinv = rsqrt(deg+1)
//   4. scale:    bucket.y *= dinv[src]   (drops the dependent dinv gather
//                                         from all 3 agg hot loops)
//   5. per layer: tiled fp32 GEMM (xW) then gather-aggregate, one wave/node,
//      lane = feature; out = dinv[d]*sum_e w*xw[src] + dinv[d]^2*xw[d] + b.
//   Bucket streams use nontemporal loads: 28.8 MB stream has no intra-pass
//   reuse and would otherwise evict the 12.8 MB xw gather operand from L2.

static __device__ __forceinline__ float4 f4zero() { return make_float4(0.f, 0.f, 0.f, 0.f); }

__global__ void fill_direct_kernel(const int* __restrict__ src, const int* __restrict__ dst,
                                   const float* __restrict__ ew, int* __restrict__ count,
                                   int2* __restrict__ bucket, int E, int C, int pad) {
    int e = blockIdx.x * blockDim.x + threadIdx.x;
    if (e >= E) return;
    int d = dst[e];
    int s = src[e];
    float w = ew[e];
    int pos = atomicAdd(&count[(size_t)d * pad], 1);
    if (pos < C) {  // capacity guard (never hit on this graph; avoids OOB)
        int2 v;
        v.x = s;
        v.y = __float_as_int(w);
        bucket[(size_t)d * C + pos] = v;
    }
}

// One wave per node: deg = sum of bucket ew, dinv = rsqrt(deg+1).
__global__ __launch_bounds__(256) void deg_dinv_kernel(const int2* __restrict__ bucket,
        const int* __restrict__ count, float* __restrict__ dinv, int N, int C, int pad) {
    int wid = (int)((blockIdx.x * blockDim.x + threadIdx.x) >> 6);
    int lane = threadIdx.x & 63;
    if (wid >= N) return;
    int cnt = min(count[(size_t)wid * pad], C);
    const unsigned long long* row = (const unsigned long long*)(bucket + (size_t)wid * C);
    float s = 0.f;
    for (int i = lane; i < cnt; i += 64) {
        unsigned long long p = __builtin_nontemporal_load(row + i);
        s += __int_as_float((int)(p >> 32));
    }
    #pragma unroll
    for (int off = 32; off > 0; off >>= 1) s += __shfl_down(s, off);
    if (lane == 0) dinv[wid] = rsqrtf(s + 1.0f);
}

// bucket.y = ew * dinv[src]  (in place)
__global__ __launch_bounds__(256) void scale_kernel(int2* __restrict__ bucket,
        const int* __restrict__ count, const float* __restrict__ dinv,
        int N, int C, int pad) {
    int wid = (int)((blockIdx.x * blockDim.x + threadIdx.x) >> 6);
    int lane = threadIdx.x & 63;
    if (wid >= N) return;
    int cnt = min(count[(size_t)wid * pad], C);
    int2* row = bucket + (size_t)wid * C;
    for (int i = lane; i < cnt; i += 64) {
        int2 v = row[i];
        v.y = __float_as_int(__int_as_float(v.y) * dinv[v.x]);
        row[i] = v;
    }
}

// Tiled fp32 GEMM: Y[N,M] = X[N,K] @ W[K,M].  64-row tiles, 4x4 register blocking.
// xs padded +4 floats/row to break the K-stride bank conflict.
template <int K, int M>
__global__ __launch_bounds__(256) void gemm_kernel(const float* __restrict__ X,
        const float* __restrict__ W, float* __restrict__ Y, int N) {
    constexpr int KP = K + 4;
    __shared__ float xs[64 * KP];
    __shared__ float ws[K * M];
    const int tid = threadIdx.x;
    const int row0 = blockIdx.x * 64;

    for (int i = tid * 4; i < K * M; i += 1024)
        *(float4*)&ws[i] = *(const float4*)&W[i];

    const int nrows = min(64, N - row0);
    for (int i = tid * 4; i < 64 * K; i += 1024) {
        int r = i / K, k = i % K;           // both multiples of 4
        float4 v = f4zero();
        if (r < nrows) v = *(const float4*)&X[(size_t)(row0 + r) * K + k];
        *(float4*)&xs[r * KP + k] = v;
    }
    __syncthreads();

    const int ct = tid & 15, rt = tid >> 4;
    const bool cok = (ct * 4 < M);          // M=40: high col-threads idle
    float acc[4][4] = {};
    for (int k = 0; k < K; ++k) {
        float a0 = xs[(rt +  0) * KP + k];
        float a1 = xs[(rt + 16) * KP + k];
        float a2 = xs[(rt + 32) * KP + k];
        float a3 = xs[(rt + 48) * KP + k];
        float4 b = cok ? *(const float4*)&ws[k * M + ct * 4] : f4zero();
        acc[0][0] += a0 * b.x; acc[0][1] += a0 * b.y; acc[0][2] += a0 * b.z; acc[0][3] += a0 * b.w;
        acc[1][0] += a1 * b.x; acc[1][1] += a1 * b.y; acc[1][2] += a1 * b.z; acc[1][3] += a1 * b.w;
        acc[2][0] += a2 * b.x; acc[2][1] += a2 * b.y; acc[2][2] += a2 * b.z; acc[2][3] += a2 * b.w;
        acc[3][0] += a3 * b.x; acc[3][1] += a3 * b.y; acc[3][2] += a3 * b.z; acc[3][3] += a3 * b.w;
    }
    if (cok) {
        #pragma unroll
        for (int i = 0; i < 4; ++i) {
            int r = row0 + rt + 16 * i;
            if (r < N) {
                float4 o = make_float4(acc[i][0], acc[i][1], acc[i][2], acc[i][3]);
                *(float4*)&Y[(size_t)r * M + ct * 4] = o;
            }
        }
    }
}

// One wave per node; lane = feature. Bucket already holds w = ew*dinv[src].
// out = dinv[n]*sum_e w*xw[src] + dinv[n]^2*xw[n] + b;  optional relu.
template <int F, bool RELU>
__global__ __launch_bounds__(256) void agg_kernel(const float* __restrict__ xw,
        const int2* __restrict__ bucket, const int* __restrict__ count,
        const float* __restrict__ dinv, const float* __restrict__ bias,
        float* __restrict__ out, int N, int C, int pad) {
    int wid = (int)((blockIdx.x * blockDim.x + threadIdx.x) >> 6);
    int lane = threadIdx.x & 63;
    if (wid >= N) return;
    int cnt = min(count[(size_t)wid * pad], C);
    const unsigned long long* row = (const unsigned long long*)(bucket + (size_t)wid * C);
    float acc = 0.f;
    int e = 0;
    for (; e + 4 <= cnt; e += 4) {
        unsigned long long p0 = __builtin_nontemporal_load(row + e);
        unsigned long long p1 = __builtin_nontemporal_load(row + e + 1);
        unsigned long long p2 = __builtin_nontemporal_load(row + e + 2);
        unsigned long long p3 = __builtin_nontemporal_load(row + e + 3);
        int   s0 = (int)p0, s1 = (int)p1, s2 = (int)p2, s3 = (int)p3;
        float w0 = __int_as_float((int)(p0 >> 32));
        float w1 = __int_as_float((int)(p1 >> 32));
        float w2 = __int_as_float((int)(p2 >> 32));
        float w3 = __int_as_float((int)(p3 >> 32));
        if (lane < F) {
            acc = fmaf(w0, xw[(size_t)s0 * F + lane], acc);
            acc = fmaf(w1, xw[(size_t)s1 * F + lane], acc);
            acc = fmaf(w2, xw[(size_t)s2 * F + lane], acc);
            acc = fmaf(w3, xw[(size_t)s3 * F + lane], acc);
        }
    }
    for (; e < cnt; ++e) {
        unsigned long long p = __builtin_nontemporal_load(row + e);
        int s = (int)p;
        float w = __int_as_float((int)(p >> 32));
        if (lane < F) acc = fmaf(w, xw[(size_t)s * F + lane], acc);
    }
    if (lane < F) {
        float dd = dinv[wid];
        acc = dd * acc + dd * dd * xw[(size_t)wid * F + lane] + bias[lane];
        if (RELU) acc = fmaxf(acc, 0.f);
        out[(size_t)wid * F + lane] = acc;
    }
}

static inline size_t ws_align(size_t x) { return (x + 255) & ~(size_t)255; }

extern "C" void kernel_launch(void* const* d_in, const int* in_sizes, int n_in,
                              void* d_out, int out_size, void* d_ws, size_t ws_size,
                              hipStream_t stream) {
    const float* x  = (const float*)d_in[0];
    const int*   ei = (const int*)d_in[1];
    const float* ew = (const float*)d_in[2];
    const float* W1 = (const float*)d_in[3];
    const float* b1 = (const float*)d_in[4];
    const float* W2 = (const float*)d_in[5];
    const float* b2 = (const float*)d_in[6];
    const float* W3 = (const float*)d_in[7];
    const float* b3 = (const float*)d_in[8];
    float* out = (float*)d_out;

    const int N = in_sizes[0] / 128;   // 50000
    const int E = in_sizes[1] / 2;     // 1600000
    const int* src = ei;
    const int* dst = ei + E;

    char* p = (char*)d_ws;
    size_t off = 0;
    auto alloc = [&](size_t bytes) -> char* {
        char* q = p + off;
        off = ws_align(off + bytes);
        return q;
    };
    float* dinv = (float*)alloc((size_t)N * 4);
    float* bufA = (float*)alloc((size_t)N * 64 * 4);
    float* bufB = (float*)alloc((size_t)N * 64 * 4);

    // Bucket capacity 72 (Poisson(32) tail; max in-degree ~63 at N=50K) is
    // non-negotiable; counter padding (anti-false-sharing) adapts to leftover ws.
    size_t remain = (ws_size > off) ? (ws_size - off) : 0;
    int C = 72;
    int pad = 16;   // 1 counter per 64B line
    while (pad > 1 &&
           ws_align((size_t)N * pad * 4) + (size_t)N * C * 8 + 512 > remain)
        pad >>= 1;
    {   // last resort: shrink C rather than OOB (should not trigger)
        size_t left = remain > ws_align((size_t)N * pad * 4) + 512
                    ? remain - ws_align((size_t)N * pad * 4) - 512 : 0;
        int cmax = (int)(left / ((size_t)N * 8));
        if (C > cmax) C = cmax;
    }
    int*  count  = (int*) alloc((size_t)N * pad * 4);
    int2* bucket = (int2*)alloc((size_t)N * (size_t)C * 8);

    hipMemsetAsync(count, 0, (size_t)N * pad * 4, stream);

    const int eb = (E + 255) / 256;
    const int gb = (N + 63) / 64;      // 782 GEMM tiles
    const int ab = (N + 3) / 4;        // one wave per node, 4 waves/block

    fill_direct_kernel<<<eb, 256, 0, stream>>>(src, dst, ew, count, bucket, E, C, pad);
    deg_dinv_kernel<<<ab, 256, 0, stream>>>(bucket, count, dinv, N, C, pad);
    scale_kernel<<<ab, 256, 0, stream>>>(bucket, count, dinv, N, C, pad);

    gemm_kernel<128, 64><<<gb, 256, 0, stream>>>(x, W1, bufA, N);
    agg_kernel<64, true><<<ab, 256, 0, stream>>>(bufA, bucket, count, dinv, b1, bufB, N, C, pad);
    gemm_kernel<64, 64><<<gb, 256, 0, stream>>>(bufB, W2, bufA, N);
    agg_kernel<64, true><<<ab, 256, 0, stream>>>(bufA, bucket, count, dinv, b2, bufB, N, C, pad);
    gemm_kernel<64, 40><<<gb, 256, 0, stream>>>(bufB, W3, bufA, N);
    agg_kernel<40, false><<<ab, 256, 0, stream>>>(bufA, bucket, count, dinv, b3, out, N, C, pad);
}

// Round 4
// 363.968 us; speedup vs baseline: 1.3674x; 1.3674x over previous
//
#include <hip/hip_runtime.h>

// GCN 3-layer: out = GCNconv3(relu(GCNconv2(relu(GCNconv1(x)))))
//
// R4: per-edge scattered global ops hit a measured ~25 G req/s device ceiling
// (R1 deg_count 22 G/s, R2/R3 fill 26 G/s). Replace atomic bucket fill with
// two-level LDS binning — near-zero scattered global traffic:
//   A. bin_scatter: 4096-edge tiles LDS-sorted by bin (bin = dst>>8, 256
//      dsts/bin), flushed as bin-contiguous coalesced runs. 1 global atomic
//      per (tile,bin), not per edge.
//   B. bin_group: one block per bin; counting-sort by dst in LDS -> exact CSR
//      (in place), plus deg/dinv computed for free in the same pass.
//   C. per layer: tiled fp32 GEMM (xW), then wave-per-node gather-aggregate
//      (R2-proven form: plain loads, in-loop dinv[src] gather).
//      out = dinv[d]*sum_e ew*dinv[s]*xw[s] + dinv[d]^2*xw[d] + b.
// NT loads removed (R3: bypassing L2 lengthened the bucket->gather dep chain).

#define TILE 4096
#define BCAP_MAX 9216   // per-bin capacity; bin count ~Binom mean 8163 sd 90

static __device__ __forceinline__ float4 f4zero() { return make_float4(0.f, 0.f, 0.f, 0.f); }

// ---------------- Pass A: tile-level LDS binning ----------------
__global__ __launch_bounds__(1024) void bin_scatter_kernel(
        const int* __restrict__ src, const int* __restrict__ dst,
        const float* __restrict__ ew, int* __restrict__ bin_cursor,
        int2* __restrict__ binned, int E, int bcap) {
    __shared__ int cnt[256];
    __shared__ int scan[256];
    __shared__ int gbase[256];
    __shared__ int2 sorted[TILE];
    __shared__ unsigned char binof[TILE];
    const int tid = threadIdx.x;
    const int e0 = blockIdx.x * TILE;

    if (tid < 256) cnt[tid] = 0;
    __syncthreads();

    int mypk[4]; float myew[4]; int mybin[4]; int myrank[4]; bool myok[4];
    #pragma unroll
    for (int j = 0; j < 4; ++j) {
        int e = e0 + j * 1024 + tid;
        myok[j] = (e < E);
        if (myok[j]) {
            int d = dst[e];
            int s = src[e];
            myew[j]   = ew[e];
            mybin[j]  = d >> 8;
            mypk[j]   = (s << 8) | (d & 255);     // src:24b | dst_local:8b
            myrank[j] = atomicAdd(&cnt[mybin[j]], 1);
        }
    }
    __syncthreads();
    if (tid < 256) scan[tid] = cnt[tid];
    __syncthreads();
    for (int off = 1; off < 256; off <<= 1) {     // inclusive Hillis-Steele
        int v = 0;
        if (tid < 256) { v = scan[tid]; if (tid >= off) v += scan[tid - off]; }
        __syncthreads();
        if (tid < 256) scan[tid] = v;
        __syncthreads();
    }
    if (tid < 256 && cnt[tid] > 0)
        gbase[tid] = atomicAdd(&bin_cursor[tid], cnt[tid]);
    __syncthreads();
    #pragma unroll
    for (int j = 0; j < 4; ++j) {
        if (myok[j]) {
            int b = mybin[j];
            int slot = (scan[b] - cnt[b]) + myrank[j];   // exclusive prefix + rank
            sorted[slot] = make_int2(mypk[j], __float_as_int(myew[j]));
            binof[slot]  = (unsigned char)b;
        }
    }
    __syncthreads();
    const int total = scan[255];
    for (int i = tid; i < total; i += 1024) {
        int b = binof[i];
        int pos = gbase[b] + (i - (scan[b] - cnt[b]));
        if (pos < bcap)   // statistically unreachable; prevents OOB
            binned[(size_t)b * bcap + pos] = sorted[i];
    }
}

// ---------------- Pass B: per-bin counting sort -> CSR (+ deg/dinv) --------
__global__ __launch_bounds__(1024) void bin_group_kernel(
        int2* __restrict__ binned, const int* __restrict__ bin_cursor,
        int* __restrict__ row_start, int* __restrict__ row_cnt,
        float* __restrict__ dinv, int N, int bcap) {
    __shared__ int   cntl[256];
    __shared__ float degl[256];
    __shared__ int   scan[256];
    __shared__ int   run[256];
    __shared__ int2  sorted[BCAP_MAX];
    const int b = blockIdx.x;
    const int tid = threadIdx.x;
    int n = bin_cursor[b];
    if (n > bcap) n = bcap;
    if (tid < 256) { cntl[tid] = 0; degl[tid] = 0.f; }
    __syncthreads();

    int2* seg = binned + (size_t)b * bcap;
    for (int i = tid; i < n; i += 1024) {
        int2 v = seg[i];
        int dl = v.x & 255;
        atomicAdd(&cntl[dl], 1);
        atomicAdd(&degl[dl], __int_as_float(v.y));
    }
    __syncthreads();
    if (tid < 256) scan[tid] = cntl[tid];
    __syncthreads();
    for (int off = 1; off < 256; off <<= 1) {
        int v = 0;
        if (tid < 256) { v = scan[tid]; if (tid >= off) v += scan[tid - off]; }
        __syncthreads();
        if (tid < 256) scan[tid] = v;
        __syncthreads();
    }
    if (tid < 256) {
        int ex = scan[tid] - cntl[tid];
        int d = (b << 8) + tid;
        if (d < N) {
            row_start[d] = b * bcap + ex;
            row_cnt[d]   = cntl[tid];
            dinv[d]      = rsqrtf(degl[tid] + 1.0f);
        }
        run[tid] = ex;
    }
    __syncthreads();
    for (int i = tid; i < n; i += 1024) {
        int2 v = seg[i];
        int dl = v.x & 255;
        int r = atomicAdd(&run[dl], 1);
        sorted[r] = make_int2(v.x >> 8, v.y);    // {src, ew}
    }
    __syncthreads();
    for (int i = tid; i < n; i += 1024)          // in-place: reads done above
        seg[i] = sorted[i];
}

// ---------------- GEMM: Y[N,M] = X[N,K] @ W[K,M] ----------------
template <int K, int M>
__global__ __launch_bounds__(256) void gemm_kernel(const float* __restrict__ X,
        const float* __restrict__ W, float* __restrict__ Y, int N) {
    constexpr int KP = K + 4;
    __shared__ float xs[64 * KP];
    __shared__ float ws[K * M];
    const int tid = threadIdx.x;
    const int row0 = blockIdx.x * 64;

    for (int i = tid * 4; i < K * M; i += 1024)
        *(float4*)&ws[i] = *(const float4*)&W[i];

    const int nrows = min(64, N - row0);
    for (int i = tid * 4; i < 64 * K; i += 1024) {
        int r = i / K, k = i % K;
        float4 v = f4zero();
        if (r < nrows) v = *(const float4*)&X[(size_t)(row0 + r) * K + k];
        *(float4*)&xs[r * KP + k] = v;
    }
    __syncthreads();

    const int ct = tid & 15, rt = tid >> 4;
    const bool cok = (ct * 4 < M);
    float acc[4][4] = {};
    for (int k = 0; k < K; ++k) {
        float a0 = xs[(rt +  0) * KP + k];
        float a1 = xs[(rt + 16) * KP + k];
        float a2 = xs[(rt + 32) * KP + k];
        float a3 = xs[(rt + 48) * KP + k];
        float4 bv = cok ? *(const float4*)&ws[k * M + ct * 4] : f4zero();
        acc[0][0] += a0 * bv.x; acc[0][1] += a0 * bv.y; acc[0][2] += a0 * bv.z; acc[0][3] += a0 * bv.w;
        acc[1][0] += a1 * bv.x; acc[1][1] += a1 * bv.y; acc[1][2] += a1 * bv.z; acc[1][3] += a1 * bv.w;
        acc[2][0] += a2 * bv.x; acc[2][1] += a2 * bv.y; acc[2][2] += a2 * bv.z; acc[2][3] += a2 * bv.w;
        acc[3][0] += a3 * bv.x; acc[3][1] += a3 * bv.y; acc[3][2] += a3 * bv.z; acc[3][3] += a3 * bv.w;
    }
    if (cok) {
        #pragma unroll
        for (int i = 0; i < 4; ++i) {
            int r = row0 + rt + 16 * i;
            if (r < N) {
                float4 o = make_float4(acc[i][0], acc[i][1], acc[i][2], acc[i][3]);
                *(float4*)&Y[(size_t)r * M + ct * 4] = o;
            }
        }
    }
}

// ---------------- Aggregate: one wave per node, lane = feature -------------
template <int F, bool RELU>
__global__ __launch_bounds__(256) void agg_kernel(const float* __restrict__ xw,
        const int2* __restrict__ csr, const int* __restrict__ row_start,
        const int* __restrict__ row_cnt, const float* __restrict__ dinv,
        const float* __restrict__ bias, float* __restrict__ out, int N) {
    int wid = (int)((blockIdx.x * blockDim.x + threadIdx.x) >> 6);
    int lane = threadIdx.x & 63;
    if (wid >= N) return;
    const int2* row = csr + row_start[wid];
    int cnt = row_cnt[wid];
    float acc = 0.f;
    int e = 0;
    for (; e + 4 <= cnt; e += 4) {
        int2 v0 = row[e], v1 = row[e + 1], v2 = row[e + 2], v3 = row[e + 3];
        float w0 = __int_as_float(v0.y) * dinv[v0.x];
        float w1 = __int_as_float(v1.y) * dinv[v1.x];
        float w2 = __int_as_float(v2.y) * dinv[v2.x];
        float w3 = __int_as_float(v3.y) * dinv[v3.x];
        if (lane < F) {
            acc = fmaf(w0, xw[(size_t)v0.x * F + lane], acc);
            acc = fmaf(w1, xw[(size_t)v1.x * F + lane], acc);
            acc = fmaf(w2, xw[(size_t)v2.x * F + lane], acc);
            acc = fmaf(w3, xw[(size_t)v3.x * F + lane], acc);
        }
    }
    for (; e < cnt; ++e) {
        int2 v = row[e];
        float w = __int_as_float(v.y) * dinv[v.x];
        if (lane < F) acc = fmaf(w, xw[(size_t)v.x * F + lane], acc);
    }
    if (lane < F) {
        float dd = dinv[wid];
        acc = dd * acc + dd * dd * xw[(size_t)wid * F + lane] + bias[lane];
        if (RELU) acc = fmaxf(acc, 0.f);
        out[(size_t)wid * F + lane] = acc;
    }
}

static inline size_t ws_align(size_t x) { return (x + 255) & ~(size_t)255; }

extern "C" void kernel_launch(void* const* d_in, const int* in_sizes, int n_in,
                              void* d_out, int out_size, void* d_ws, size_t ws_size,
                              hipStream_t stream) {
    const float* x  = (const float*)d_in[0];
    const int*   ei = (const int*)d_in[1];
    const float* ew = (const float*)d_in[2];
    const float* W1 = (const float*)d_in[3];
    const float* b1 = (const float*)d_in[4];
    const float* W2 = (const float*)d_in[5];
    const float* b2 = (const float*)d_in[6];
    const float* W3 = (const float*)d_in[7];
    const float* b3 = (const float*)d_in[8];
    float* out = (float*)d_out;

    const int N = in_sizes[0] / 128;   // 50000
    const int E = in_sizes[1] / 2;     // 1600000
    const int* src = ei;
    const int* dst = ei + E;
    const int nbins = (N + 255) >> 8;  // 196

    char* p = (char*)d_ws;
    size_t off = 0;
    auto alloc = [&](size_t bytes) -> char* {
        char* q = p + off;
        off = ws_align(off + bytes);
        return q;
    };
    int*   row_start  = (int*)  alloc((size_t)N * 4);
    int*   row_cnt    = (int*)  alloc((size_t)N * 4);
    float* dinv       = (float*)alloc((size_t)N * 4);
    int*   bin_cursor = (int*)  alloc((size_t)nbins * 4);
    float* bufA       = (float*)alloc((size_t)N * 64 * 4);
    float* bufB       = (float*)alloc((size_t)N * 64 * 4);
    size_t remain = (ws_size > off) ? (ws_size - off) : 0;
    int bcap = (int)(remain / ((size_t)nbins * 8));
    if (bcap > BCAP_MAX) bcap = BCAP_MAX;
    int2* binned = (int2*)alloc((size_t)nbins * (size_t)bcap * 8);

    hipMemsetAsync(bin_cursor, 0, (size_t)nbins * 4, stream);

    const int tb = (E + TILE - 1) / TILE;   // 391 tiles
    const int gb = (N + 63) / 64;           // 782 GEMM tiles
    const int ab = (N + 3) / 4;             // one wave per node

    bin_scatter_kernel<<<tb, 1024, 0, stream>>>(src, dst, ew, bin_cursor, binned, E, bcap);
    bin_group_kernel<<<nbins, 1024, 0, stream>>>(binned, bin_cursor, row_start, row_cnt, dinv, N, bcap);

    gemm_kernel<128, 64><<<gb, 256, 0, stream>>>(x, W1, bufA, N);
    agg_kernel<64, true><<<ab, 256, 0, stream>>>(bufA, binned, row_start, row_cnt, dinv, b1, bufB, N);
    gemm_kernel<64, 64><<<gb, 256, 0, stream>>>(bufB, W2, bufA, N);
    agg_kernel<64, true><<<ab, 256, 0, stream>>>(bufA, binned, row_start, row_cnt, dinv, b2, bufB, N);
    gemm_kernel<64, 40><<<gb, 256, 0, stream>>>(bufB, W3, bufA, N);
    agg_kernel<40, false><<<ab, 256, 0, stream>>>(bufA, binned, row_start, row_cnt, dinv, b3, out, N);
}

// Round 5
// 349.085 us; speedup vs baseline: 1.4257x; 1.0426x over previous
//
#include <hip/hip_runtime.h>

// GCN 3-layer: out = GCNconv3(relu(GCNconv2(relu(GCNconv1(x)))))
//
// R5: agg is bound by gathered-row byte traffic (R4: 410 MB L2-request /
// 160 MB L2-miss per agg at ~2.7 TB/s to L3). Store xw in bf16 (RNE in the
// GEMM epilogue, fp32 accumulate in agg) -> gathered row 256 B -> 128 B,
// halving the dominant term. Agg unroll 4 -> 8 for 2x outstanding loads.
// Error budget: bf16 RNE 2^-9 relative; Sum|w|*dinv_d ~ 0.5 over ~32 edges
// -> per-layer absmax ~5e-4; total ~2-3e-3 < 6.445e-3 threshold.
//
// Pipeline (R4-proven):
//   A. bin_scatter: 4096-edge tiles LDS-sorted by bin (bin = dst>>8),
//      flushed as bin-contiguous coalesced runs; 1 global atomic/(tile,bin).
//   B. bin_group: one block per bin; LDS counting-sort by dst -> exact CSR
//      in place + deg/dinv for free.
//   C. per layer: fp32 GEMM (xW) -> bf16 Y; wave-per-node gather-aggregate;
//      out = dinv[d]*sum_e ew*dinv[s]*xw[s] + dinv[d]^2*xw[d] + b (fp32).

#define TILE 4096
#define BCAP_MAX 9216   // per-bin capacity; bin load ~Binom mean 8163 sd 90

static __device__ __forceinline__ float4 f4zero() { return make_float4(0.f, 0.f, 0.f, 0.f); }

static __device__ __forceinline__ unsigned short f2bf_rne(float x) {
    unsigned u = __float_as_uint(x);
    u += 0x7FFFu + ((u >> 16) & 1u);     // round-to-nearest-even
    return (unsigned short)(u >> 16);
}
static __device__ __forceinline__ float bf2f(unsigned short b) {
    return __uint_as_float((unsigned)b << 16);
}

// ---------------- Pass A: tile-level LDS binning ----------------
__global__ __launch_bounds__(1024) void bin_scatter_kernel(
        const int* __restrict__ src, const int* __restrict__ dst,
        const float* __restrict__ ew, int* __restrict__ bin_cursor,
        int2* __restrict__ binned, int E, int bcap) {
    __shared__ int cnt[256];
    __shared__ int scan[256];
    __shared__ int gbase[256];
    __shared__ int2 sorted[TILE];
    __shared__ unsigned char binof[TILE];
    const int tid = threadIdx.x;
    const int e0 = blockIdx.x * TILE;

    if (tid < 256) cnt[tid] = 0;
    __syncthreads();

    int mypk[4]; float myew[4]; int mybin[4]; int myrank[4]; bool myok[4];
    #pragma unroll
    for (int j = 0; j < 4; ++j) {
        int e = e0 + j * 1024 + tid;
        myok[j] = (e < E);
        if (myok[j]) {
            int d = dst[e];
            int s = src[e];
            myew[j]   = ew[e];
            mybin[j]  = d >> 8;
            mypk[j]   = (s << 8) | (d & 255);     // src:24b | dst_local:8b
            myrank[j] = atomicAdd(&cnt[mybin[j]], 1);
        }
    }
    __syncthreads();
    if (tid < 256) scan[tid] = cnt[tid];
    __syncthreads();
    for (int off = 1; off < 256; off <<= 1) {     // inclusive Hillis-Steele
        int v = 0;
        if (tid < 256) { v = scan[tid]; if (tid >= off) v += scan[tid - off]; }
        __syncthreads();
        if (tid < 256) scan[tid] = v;
        __syncthreads();
    }
    if (tid < 256 && cnt[tid] > 0)
        gbase[tid] = atomicAdd(&bin_cursor[tid], cnt[tid]);
    __syncthreads();
    #pragma unroll
    for (int j = 0; j < 4; ++j) {
        if (myok[j]) {
            int b = mybin[j];
            int slot = (scan[b] - cnt[b]) + myrank[j];   // excl prefix + rank
            sorted[slot] = make_int2(mypk[j], __float_as_int(myew[j]));
            binof[slot]  = (unsigned char)b;
        }
    }
    __syncthreads();
    const int total = scan[255];
    for (int i = tid; i < total; i += 1024) {
        int b = binof[i];
        int pos = gbase[b] + (i - (scan[b] - cnt[b]));
        if (pos < bcap)   // statistically unreachable; prevents OOB
            binned[(size_t)b * bcap + pos] = sorted[i];
    }
}

// ---------------- Pass B: per-bin counting sort -> CSR (+ deg/dinv) --------
__global__ __launch_bounds__(1024) void bin_group_kernel(
        int2* __restrict__ binned, const int* __restrict__ bin_cursor,
        int* __restrict__ row_start, int* __restrict__ row_cnt,
        float* __restrict__ dinv, int N, int bcap) {
    __shared__ int   cntl[256];
    __shared__ float degl[256];
    __shared__ int   scan[256];
    __shared__ int   run[256];
    __shared__ int2  sorted[BCAP_MAX];
    const int b = blockIdx.x;
    const int tid = threadIdx.x;
    int n = bin_cursor[b];
    if (n > bcap) n = bcap;
    if (tid < 256) { cntl[tid] = 0; degl[tid] = 0.f; }
    __syncthreads();

    int2* seg = binned + (size_t)b * bcap;
    for (int i = tid; i < n; i += 1024) {
        int2 v = seg[i];
        int dl = v.x & 255;
        atomicAdd(&cntl[dl], 1);
        atomicAdd(&degl[dl], __int_as_float(v.y));
    }
    __syncthreads();
    if (tid < 256) scan[tid] = cntl[tid];
    __syncthreads();
    for (int off = 1; off < 256; off <<= 1) {
        int v = 0;
        if (tid < 256) { v = scan[tid]; if (tid >= off) v += scan[tid - off]; }
        __syncthreads();
        if (tid < 256) scan[tid] = v;
        __syncthreads();
    }
    if (tid < 256) {
        int ex = scan[tid] - cntl[tid];
        int d = (b << 8) + tid;
        if (d < N) {
            row_start[d] = b * bcap + ex;
            row_cnt[d]   = cntl[tid];
            dinv[d]      = rsqrtf(degl[tid] + 1.0f);
        }
        run[tid] = ex;
    }
    __syncthreads();
    for (int i = tid; i < n; i += 1024) {
        int2 v = seg[i];
        int dl = v.x & 255;
        int r = atomicAdd(&run[dl], 1);
        sorted[r] = make_int2(v.x >> 8, v.y);    // {src, ew}
    }
    __syncthreads();
    for (int i = tid; i < n; i += 1024)          // in-place: reads done above
        seg[i] = sorted[i];
}

// ------- GEMM: Y[N,M](bf16) = X[N,K](fp32) @ W[K,M](fp32), RNE epilogue ----
template <int K, int M>
__global__ __launch_bounds__(256) void gemm_kernel(const float* __restrict__ X,
        const float* __restrict__ W, unsigned short* __restrict__ Y, int N) {
    constexpr int KP = K + 4;
    __shared__ float xs[64 * KP];
    __shared__ float ws[K * M];
    const int tid = threadIdx.x;
    const int row0 = blockIdx.x * 64;

    for (int i = tid * 4; i < K * M; i += 1024)
        *(float4*)&ws[i] = *(const float4*)&W[i];

    const int nrows = min(64, N - row0);
    for (int i = tid * 4; i < 64 * K; i += 1024) {
        int r = i / K, k = i % K;
        float4 v = f4zero();
        if (r < nrows) v = *(const float4*)&X[(size_t)(row0 + r) * K + k];
        *(float4*)&xs[r * KP + k] = v;
    }
    __syncthreads();

    const int ct = tid & 15, rt = tid >> 4;
    const bool cok = (ct * 4 < M);
    float acc[4][4] = {};
    for (int k = 0; k < K; ++k) {
        float a0 = xs[(rt +  0) * KP + k];
        float a1 = xs[(rt + 16) * KP + k];
        float a2 = xs[(rt + 32) * KP + k];
        float a3 = xs[(rt + 48) * KP + k];
        float4 bv = cok ? *(const float4*)&ws[k * M + ct * 4] : f4zero();
        acc[0][0] += a0 * bv.x; acc[0][1] += a0 * bv.y; acc[0][2] += a0 * bv.z; acc[0][3] += a0 * bv.w;
        acc[1][0] += a1 * bv.x; acc[1][1] += a1 * bv.y; acc[1][2] += a1 * bv.z; acc[1][3] += a1 * bv.w;
        acc[2][0] += a2 * bv.x; acc[2][1] += a2 * bv.y; acc[2][2] += a2 * bv.z; acc[2][3] += a2 * bv.w;
        acc[3][0] += a3 * bv.x; acc[3][1] += a3 * bv.y; acc[3][2] += a3 * bv.z; acc[3][3] += a3 * bv.w;
    }
    if (cok) {
        #pragma unroll
        for (int i = 0; i < 4; ++i) {
            int r = row0 + rt + 16 * i;
            if (r < N) {
                ushort4 o;
                o.x = f2bf_rne(acc[i][0]); o.y = f2bf_rne(acc[i][1]);
                o.z = f2bf_rne(acc[i][2]); o.w = f2bf_rne(acc[i][3]);
                *(ushort4*)&Y[(size_t)r * M + ct * 4] = o;
            }
        }
    }
}

// ---------------- Aggregate: one wave per node, lane = feature -------------
// xw is bf16 (128B/row gather for F=64); accumulate fp32; out fp32.
template <int F, bool RELU>
__global__ __launch_bounds__(256) void agg_kernel(const unsigned short* __restrict__ xw,
        const int2* __restrict__ csr, const int* __restrict__ row_start,
        const int* __restrict__ row_cnt, const float* __restrict__ dinv,
        const float* __restrict__ bias, float* __restrict__ out, int N) {
    int wid = (int)((blockIdx.x * blockDim.x + threadIdx.x) >> 6);
    int lane = threadIdx.x & 63;
    if (wid >= N) return;
    const int2* row = csr + row_start[wid];
    int cnt = row_cnt[wid];
    float acc = 0.f;
    int e = 0;
    for (; e + 8 <= cnt; e += 8) {
        int2 v[8];
        #pragma unroll
        for (int j = 0; j < 8; ++j) v[j] = row[e + j];
        float w[8];
        #pragma unroll
        for (int j = 0; j < 8; ++j) w[j] = __int_as_float(v[j].y) * dinv[v[j].x];
        if (lane < F) {
            #pragma unroll
            for (int j = 0; j < 8; ++j)
                acc = fmaf(w[j], bf2f(xw[(size_t)v[j].x * F + lane]), acc);
        }
    }
    for (; e < cnt; ++e) {
        int2 v = row[e];
        float w = __int_as_float(v.y) * dinv[v.x];
        if (lane < F) acc = fmaf(w, bf2f(xw[(size_t)v.x * F + lane]), acc);
    }
    if (lane < F) {
        float dd = dinv[wid];
        acc = dd * acc + dd * dd * bf2f(xw[(size_t)wid * F + lane]) + bias[lane];
        if (RELU) acc = fmaxf(acc, 0.f);
        out[(size_t)wid * F + lane] = acc;
    }
}

static inline size_t ws_align(size_t x) { return (x + 255) & ~(size_t)255; }

extern "C" void kernel_launch(void* const* d_in, const int* in_sizes, int n_in,
                              void* d_out, int out_size, void* d_ws, size_t ws_size,
                              hipStream_t stream) {
    const float* x  = (const float*)d_in[0];
    const int*   ei = (const int*)d_in[1];
    const float* ew = (const float*)d_in[2];
    const float* W1 = (const float*)d_in[3];
    const float* b1 = (const float*)d_in[4];
    const float* W2 = (const float*)d_in[5];
    const float* b2 = (const float*)d_in[6];
    const float* W3 = (const float*)d_in[7];
    const float* b3 = (const float*)d_in[8];
    float* out = (float*)d_out;

    const int N = in_sizes[0] / 128;   // 50000
    const int E = in_sizes[1] / 2;     // 1600000
    const int* src = ei;
    const int* dst = ei + E;
    const int nbins = (N + 255) >> 8;  // 196

    char* p = (char*)d_ws;
    size_t off = 0;
    auto alloc = [&](size_t bytes) -> char* {
        char* q = p + off;
        off = ws_align(off + bytes);
        return q;
    };
    int*   row_start  = (int*)  alloc((size_t)N * 4);
    int*   row_cnt    = (int*)  alloc((size_t)N * 4);
    float* dinv       = (float*)alloc((size_t)N * 4);
    int*   bin_cursor = (int*)  alloc((size_t)nbins * 4);
    unsigned short* xwbuf = (unsigned short*)alloc((size_t)N * 64 * 2);  // bf16 xW
    float* hbuf       = (float*)alloc((size_t)N * 64 * 4);               // fp32 h
    size_t remain = (ws_size > off) ? (ws_size - off) : 0;
    int bcap = (int)(remain / ((size_t)nbins * 8));
    if (bcap > BCAP_MAX) bcap = BCAP_MAX;
    int2* binned = (int2*)alloc((size_t)nbins * (size_t)bcap * 8);

    hipMemsetAsync(bin_cursor, 0, (size_t)nbins * 4, stream);

    const int tb = (E + TILE - 1) / TILE;   // 391 tiles
    const int gb = (N + 63) / 64;           // 782 GEMM tiles
    const int ab = (N + 3) / 4;             // one wave per node

    bin_scatter_kernel<<<tb, 1024, 0, stream>>>(src, dst, ew, bin_cursor, binned, E, bcap);
    bin_group_kernel<<<nbins, 1024, 0, stream>>>(binned, bin_cursor, row_start, row_cnt, dinv, N, bcap);

    gemm_kernel<128, 64><<<gb, 256, 0, stream>>>(x, W1, xwbuf, N);
    agg_kernel<64, true><<<ab, 256, 0, stream>>>(xwbuf, binned, row_start, row_cnt, dinv, b1, hbuf, N);
    gemm_kernel<64, 64><<<gb, 256, 0, stream>>>(hbuf, W2, xwbuf, N);
    agg_kernel<64, true><<<ab, 256, 0, stream>>>(xwbuf, binned, row_start, row_cnt, dinv, b2, hbuf, N);
    gemm_kernel<64, 40><<<gb, 256, 0, stream>>>(hbuf, W3, xwbuf, N);
    agg_kernel<40, false><<<ab, 256, 0, stream>>>(xwbuf, binned, row_start, row_cnt, dinv, b3, out, N);
}

// Round 6
// 288.158 us; speedup vs baseline: 1.7272x; 1.2114x over previous
//
#include <hip/hip_runtime.h>

// GCN 3-layer: out = GCNconv3(relu(GCNconv2(relu(GCNconv1(x)))))
//
// R6: R5 post-mortem showed agg is VMEM-instruction-issue bound (~24.5
// cyc/edge/CU; 3 vmem instrs/edge), NOT byte-bound (FETCH dropped 4x with
// no time change). Cut to 1 vmem/edge:
//   - edge list read scalarized: one lane-indexed int2 load covers 64 edges;
//     per-edge {src,w} broadcast via v_readlane (VALU, no memory op).
//   - dinv[src] folded into GEMM epilogue: xws[s] = bf16(dinv[s]*xw[s]);
//     out = dinv[d]*(sum_e ew*xws[s] + xws[d]) + b. No dinv gather in agg.
//   - 2 accumulators to shorten the dependent-fma chain.
//
// Pipeline (R4-proven preprocessing):
//   A. bin_scatter: 4096-edge tiles LDS-sorted by bin (bin = dst>>8),
//      flushed as bin-contiguous coalesced runs; 1 global atomic/(tile,bin).
//   B. bin_group: one block per bin; LDS counting-sort by dst -> exact CSR
//      in place + deg/dinv for free.
//   C. per layer: fp32 GEMM -> bf16 dinv-prescaled Y; wave-per-node agg.

#define TILE 4096
#define BCAP_MAX 9216   // per-bin capacity; bin load ~Binom mean 8163 sd 90

static __device__ __forceinline__ float4 f4zero() { return make_float4(0.f, 0.f, 0.f, 0.f); }

static __device__ __forceinline__ unsigned short f2bf_rne(float x) {
    unsigned u = __float_as_uint(x);
    u += 0x7FFFu + ((u >> 16) & 1u);     // round-to-nearest-even
    return (unsigned short)(u >> 16);
}
static __device__ __forceinline__ float bf2f(unsigned short b) {
    return __uint_as_float((unsigned)b << 16);
}

// ---------------- Pass A: tile-level LDS binning ----------------
__global__ __launch_bounds__(1024) void bin_scatter_kernel(
        const int* __restrict__ src, const int* __restrict__ dst,
        const float* __restrict__ ew, int* __restrict__ bin_cursor,
        int2* __restrict__ binned, int E, int bcap) {
    __shared__ int cnt[256];
    __shared__ int scan[256];
    __shared__ int gbase[256];
    __shared__ int2 sorted[TILE];
    __shared__ unsigned char binof[TILE];
    const int tid = threadIdx.x;
    const int e0 = blockIdx.x * TILE;

    if (tid < 256) cnt[tid] = 0;
    __syncthreads();

    int mypk[4]; float myew[4]; int mybin[4]; int myrank[4]; bool myok[4];
    #pragma unroll
    for (int j = 0; j < 4; ++j) {
        int e = e0 + j * 1024 + tid;
        myok[j] = (e < E);
        if (myok[j]) {
            int d = dst[e];
            int s = src[e];
            myew[j]   = ew[e];
            mybin[j]  = d >> 8;
            mypk[j]   = (s << 8) | (d & 255);     // src:24b | dst_local:8b
            myrank[j] = atomicAdd(&cnt[mybin[j]], 1);
        }
    }
    __syncthreads();
    if (tid < 256) scan[tid] = cnt[tid];
    __syncthreads();
    for (int off = 1; off < 256; off <<= 1) {     // inclusive Hillis-Steele
        int v = 0;
        if (tid < 256) { v = scan[tid]; if (tid >= off) v += scan[tid - off]; }
        __syncthreads();
        if (tid < 256) scan[tid] = v;
        __syncthreads();
    }
    if (tid < 256 && cnt[tid] > 0)
        gbase[tid] = atomicAdd(&bin_cursor[tid], cnt[tid]);
    __syncthreads();
    #pragma unroll
    for (int j = 0; j < 4; ++j) {
        if (myok[j]) {
            int b = mybin[j];
            int slot = (scan[b] - cnt[b]) + myrank[j];   // excl prefix + rank
            sorted[slot] = make_int2(mypk[j], __float_as_int(myew[j]));
            binof[slot]  = (unsigned char)b;
        }
    }
    __syncthreads();
    const int total = scan[255];
    for (int i = tid; i < total; i += 1024) {
        int b = binof[i];
        int pos = gbase[b] + (i - (scan[b] - cnt[b]));
        if (pos < bcap)   // statistically unreachable; prevents OOB
            binned[(size_t)b * bcap + pos] = sorted[i];
    }
}

// ---------------- Pass B: per-bin counting sort -> CSR (+ deg/dinv) --------
__global__ __launch_bounds__(1024) void bin_group_kernel(
        int2* __restrict__ binned, const int* __restrict__ bin_cursor,
        int* __restrict__ row_start, int* __restrict__ row_cnt,
        float* __restrict__ dinv, int N, int bcap) {
    __shared__ int   cntl[256];
    __shared__ float degl[256];
    __shared__ int   scan[256];
    __shared__ int   run[256];
    __shared__ int2  sorted[BCAP_MAX];
    const int b = blockIdx.x;
    const int tid = threadIdx.x;
    int n = bin_cursor[b];
    if (n > bcap) n = bcap;
    if (tid < 256) { cntl[tid] = 0; degl[tid] = 0.f; }
    __syncthreads();

    int2* seg = binned + (size_t)b * bcap;
    for (int i = tid; i < n; i += 1024) {
        int2 v = seg[i];
        int dl = v.x & 255;
        atomicAdd(&cntl[dl], 1);
        atomicAdd(&degl[dl], __int_as_float(v.y));
    }
    __syncthreads();
    if (tid < 256) scan[tid] = cntl[tid];
    __syncthreads();
    for (int off = 1; off < 256; off <<= 1) {
        int v = 0;
        if (tid < 256) { v = scan[tid]; if (tid >= off) v += scan[tid - off]; }
        __syncthreads();
        if (tid < 256) scan[tid] = v;
        __syncthreads();
    }
    if (tid < 256) {
        int ex = scan[tid] - cntl[tid];
        int d = (b << 8) + tid;
        if (d < N) {
            row_start[d] = b * bcap + ex;
            row_cnt[d]   = cntl[tid];
            dinv[d]      = rsqrtf(degl[tid] + 1.0f);
        }
        run[tid] = ex;
    }
    __syncthreads();
    for (int i = tid; i < n; i += 1024) {
        int2 v = seg[i];
        int dl = v.x & 255;
        int r = atomicAdd(&run[dl], 1);
        sorted[r] = make_int2(v.x >> 8, v.y);    // {src, ew}
    }
    __syncthreads();
    for (int i = tid; i < n; i += 1024)          // in-place: reads done above
        seg[i] = sorted[i];
}

// --- GEMM: Y[N,M](bf16) = dinv[r] * (X[N,K](fp32) @ W[K,M](fp32)), RNE -----
template <int K, int M>
__global__ __launch_bounds__(256) void gemm_kernel(const float* __restrict__ X,
        const float* __restrict__ W, const float* __restrict__ dinv,
        unsigned short* __restrict__ Y, int N) {
    constexpr int KP = K + 4;
    __shared__ float xs[64 * KP];
    __shared__ float ws[K * M];
    const int tid = threadIdx.x;
    const int row0 = blockIdx.x * 64;

    for (int i = tid * 4; i < K * M; i += 1024)
        *(float4*)&ws[i] = *(const float4*)&W[i];

    const int nrows = min(64, N - row0);
    for (int i = tid * 4; i < 64 * K; i += 1024) {
        int r = i / K, k = i % K;
        float4 v = f4zero();
        if (r < nrows) v = *(const float4*)&X[(size_t)(row0 + r) * K + k];
        *(float4*)&xs[r * KP + k] = v;
    }
    __syncthreads();

    const int ct = tid & 15, rt = tid >> 4;
    const bool cok = (ct * 4 < M);
    float acc[4][4] = {};
    for (int k = 0; k < K; ++k) {
        float a0 = xs[(rt +  0) * KP + k];
        float a1 = xs[(rt + 16) * KP + k];
        float a2 = xs[(rt + 32) * KP + k];
        float a3 = xs[(rt + 48) * KP + k];
        float4 bv = cok ? *(const float4*)&ws[k * M + ct * 4] : f4zero();
        acc[0][0] += a0 * bv.x; acc[0][1] += a0 * bv.y; acc[0][2] += a0 * bv.z; acc[0][3] += a0 * bv.w;
        acc[1][0] += a1 * bv.x; acc[1][1] += a1 * bv.y; acc[1][2] += a1 * bv.z; acc[1][3] += a1 * bv.w;
        acc[2][0] += a2 * bv.x; acc[2][1] += a2 * bv.y; acc[2][2] += a2 * bv.z; acc[2][3] += a2 * bv.w;
        acc[3][0] += a3 * bv.x; acc[3][1] += a3 * bv.y; acc[3][2] += a3 * bv.z; acc[3][3] += a3 * bv.w;
    }
    if (cok) {
        #pragma unroll
        for (int i = 0; i < 4; ++i) {
            int r = row0 + rt + 16 * i;
            if (r < N) {
                float dd = dinv[r];
                ushort4 o;
                o.x = f2bf_rne(acc[i][0] * dd); o.y = f2bf_rne(acc[i][1] * dd);
                o.z = f2bf_rne(acc[i][2] * dd); o.w = f2bf_rne(acc[i][3] * dd);
                *(ushort4*)&Y[(size_t)r * M + ct * 4] = o;
            }
        }
    }
}

// ---------------- Aggregate: one wave per node, lane = feature -------------
// xw holds bf16 dinv-prescaled rows. 1 vmem instr per edge (the row gather);
// edge {src,w} comes from a lane-indexed block load + v_readlane broadcast.
// out = dinv[d]*(sum_e ew*xw[s] + xw[d]) + b.
// NOTE: lanes >= F compute garbage from in-bounds reads (row stride padded by
// the 64-wide allocation) and never store.
template <int F, bool RELU>
__global__ __launch_bounds__(256) void agg_kernel(const unsigned short* __restrict__ xw,
        const int2* __restrict__ csr, const int* __restrict__ row_start,
        const int* __restrict__ row_cnt, const float* __restrict__ dinv,
        const float* __restrict__ bias, float* __restrict__ out, int N) {
    int wid = (int)((blockIdx.x * blockDim.x + threadIdx.x) >> 6);
    int lane = threadIdx.x & 63;
    if (wid >= N) return;
    const int2* row = csr + row_start[wid];
    int cnt = row_cnt[wid];
    float acc0 = 0.f, acc1 = 0.f;
    for (int base = 0; base < cnt; base += 64) {
        int m = min(cnt - base, 64);
        int2 ed = make_int2(0, 0);
        if (lane < m) ed = row[base + lane];
        int j = 0;
        for (; j + 8 <= m; j += 8) {
            #pragma unroll
            for (int u = 0; u < 8; u += 2) {
                int s0 = __builtin_amdgcn_readlane(ed.x, j + u);
                int w0 = __builtin_amdgcn_readlane(ed.y, j + u);
                int s1 = __builtin_amdgcn_readlane(ed.x, j + u + 1);
                int w1 = __builtin_amdgcn_readlane(ed.y, j + u + 1);
                acc0 = fmaf(__int_as_float(w0), bf2f(xw[(size_t)s0 * F + lane]), acc0);
                acc1 = fmaf(__int_as_float(w1), bf2f(xw[(size_t)s1 * F + lane]), acc1);
            }
        }
        for (; j < m; ++j) {
            int s = __builtin_amdgcn_readlane(ed.x, j);
            int w = __builtin_amdgcn_readlane(ed.y, j);
            acc0 = fmaf(__int_as_float(w), bf2f(xw[(size_t)s * F + lane]), acc0);
        }
    }
    if (lane < F) {
        float dd = dinv[wid];
        float selfv = bf2f(xw[(size_t)wid * F + lane]);   // already dinv-scaled
        float acc = dd * (acc0 + acc1 + selfv) + bias[lane];
        if (RELU) acc = fmaxf(acc, 0.f);
        out[(size_t)wid * F + lane] = acc;
    }
}

static inline size_t ws_align(size_t x) { return (x + 255) & ~(size_t)255; }

extern "C" void kernel_launch(void* const* d_in, const int* in_sizes, int n_in,
                              void* d_out, int out_size, void* d_ws, size_t ws_size,
                              hipStream_t stream) {
    const float* x  = (const float*)d_in[0];
    const int*   ei = (const int*)d_in[1];
    const float* ew = (const float*)d_in[2];
    const float* W1 = (const float*)d_in[3];
    const float* b1 = (const float*)d_in[4];
    const float* W2 = (const float*)d_in[5];
    const float* b2 = (const float*)d_in[6];
    const float* W3 = (const float*)d_in[7];
    const float* b3 = (const float*)d_in[8];
    float* out = (float*)d_out;

    const int N = in_sizes[0] / 128;   // 50000
    const int E = in_sizes[1] / 2;     // 1600000
    const int* src = ei;
    const int* dst = ei + E;
    const int nbins = (N + 255) >> 8;  // 196

    char* p = (char*)d_ws;
    size_t off = 0;
    auto alloc = [&](size_t bytes) -> char* {
        char* q = p + off;
        off = ws_align(off + bytes);
        return q;
    };
    int*   row_start  = (int*)  alloc((size_t)N * 4);
    int*   row_cnt    = (int*)  alloc((size_t)N * 4);
    float* dinv       = (float*)alloc((size_t)N * 4);
    int*   bin_cursor = (int*)  alloc((size_t)nbins * 4);
    unsigned short* xwbuf = (unsigned short*)alloc((size_t)N * 64 * 2);  // bf16 dinv*xW
    float* hbuf       = (float*)alloc((size_t)N * 64 * 4);               // fp32 h
    size_t remain = (ws_size > off) ? (ws_size - off) : 0;
    int bcap = (int)(remain / ((size_t)nbins * 8));
    if (bcap > BCAP_MAX) bcap = BCAP_MAX;
    int2* binned = (int2*)alloc((size_t)nbins * (size_t)bcap * 8);

    hipMemsetAsync(bin_cursor, 0, (size_t)nbins * 4, stream);

    const int tb = (E + TILE - 1) / TILE;   // 391 tiles
    const int gb = (N + 63) / 64;           // 782 GEMM tiles
    const int ab = (N + 3) / 4;             // one wave per node

    bin_scatter_kernel<<<tb, 1024, 0, stream>>>(src, dst, ew, bin_cursor, binned, E, bcap);
    bin_group_kernel<<<nbins, 1024, 0, stream>>>(binned, bin_cursor, row_start, row_cnt, dinv, N, bcap);

    gemm_kernel<128, 64><<<gb, 256, 0, stream>>>(x, W1, dinv, xwbuf, N);
    agg_kernel<64, true><<<ab, 256, 0, stream>>>(xwbuf, binned, row_start, row_cnt, dinv, b1, hbuf, N);
    gemm_kernel<64, 64><<<gb, 256, 0, stream>>>(hbuf, W2, dinv, xwbuf, N);
    agg_kernel<64, true><<<ab, 256, 0, stream>>>(xwbuf, binned, row_start, row_cnt, dinv, b2, hbuf, N);
    gemm_kernel<64, 40><<<gb, 256, 0, stream>>>(hbuf, W3, dinv, xwbuf, N);
    agg_kernel<40, false><<<ab, 256, 0, stream>>>(xwbuf, binned, row_start, row_cnt, dinv, b3, out, N);
}